// Round 1
// baseline (2496.302 us; speedup 1.0000x reference)
//
#include <hip/hip_runtime.h>

#define DIM_IN 128
#define NREL 4
#define KTOT (DIM_IN + NREL * DIM_IN)  // 640

// ---------------- degree ----------------
__global__ void deg_kernel(const int* __restrict__ ei, const int* __restrict__ et,
                           float* __restrict__ deg, int E) {
    int e = blockIdx.x * 256 + threadIdx.x;
    if (e >= E) return;
    int dst = ei[E + e];
    int r = et[e];
    unsafeAtomicAdd(&deg[(size_t)dst * NREL + r], 1.0f);
}

__global__ void inv_kernel(float* __restrict__ deg, int n) {
    int i = blockIdx.x * 256 + threadIdx.x;
    if (i < n) deg[i] = 1.0f / fmaxf(deg[i], 1.0f);
}

// ---------------- scatter-add: agg[dst][r][:] += feat[src][:] ----------------
// 256 threads = 8 edges/block, 32 lanes per edge, float4 per lane.
__global__ __launch_bounds__(256) void scatter_kernel(
    const float* __restrict__ feat, const int* __restrict__ ei,
    const int* __restrict__ et, float* __restrict__ agg, int E) {
    int lane = threadIdx.x & 31;
    int esub = threadIdx.x >> 5;
    int e = blockIdx.x * 8 + esub;
    if (e >= E) return;
    int src = ei[e];
    int dst = ei[E + e];
    int r = et[e];
    float4 v = ((const float4*)(feat + (size_t)src * DIM_IN))[lane];
    float* d = agg + (size_t)dst * (NREL * DIM_IN) + r * DIM_IN + lane * 4;
    unsafeAtomicAdd(d + 0, v.x);
    unsafeAtomicAdd(d + 1, v.y);
    unsafeAtomicAdd(d + 2, v.z);
    unsafeAtomicAdd(d + 3, v.w);
}

// ---------------- GEMM: out = [X | inv*agg] @ [Wroot; Wrel] + bias ----------------
// BM=64, BK=32, BN=NOUT. 256 threads; thread (tx,ty) owns rows ty+8m, cols tx+32c.
template <int NOUT, bool RELU>
__global__ __launch_bounds__(256) void gemm_kernel(
    const float* __restrict__ X,      // [N,128]
    const float* __restrict__ agg,    // [N,512]
    const float* __restrict__ inv,    // [N,4]
    const float* __restrict__ Wroot,  // [128,NOUT]
    const float* __restrict__ Wrel,   // [512,NOUT]
    const float* __restrict__ bias,   // [NOUT]
    float* __restrict__ out,          // [N,NOUT]
    int N) {
    constexpr int NC = NOUT / 32;
    __shared__ float sA[64][36];  // stride 36: float4 stores land <=2-way (free)
    __shared__ float sB[32][NOUT];
    const int t = threadIdx.x;
    const int tx = t & 31, ty = t >> 5;
    const int m0 = blockIdx.x * 64;

    float acc[8][NC];
#pragma unroll
    for (int m = 0; m < 8; m++)
#pragma unroll
        for (int c = 0; c < NC; c++) acc[m][c] = 0.f;

    for (int k0 = 0; k0 < KTOT; k0 += 32) {
        // stage A: 64 rows x 32 k = 512 float4, 2 per thread
#pragma unroll
        for (int q = 0; q < 2; q++) {
            int idx4 = t + q * 256;
            int row = idx4 >> 3, kc = idx4 & 7;
            int rowg = m0 + row;
            float4 v = make_float4(0.f, 0.f, 0.f, 0.f);
            if (rowg < N) {
                if (k0 < DIM_IN) {
                    v = *(const float4*)(X + (size_t)rowg * DIM_IN + k0 + kc * 4);
                } else {
                    v = *(const float4*)(agg + (size_t)rowg * (NREL * DIM_IN) +
                                         (k0 - DIM_IN) + kc * 4);
                    float s = inv[(size_t)rowg * NREL + ((k0 - DIM_IN) >> 7)];
                    v.x *= s; v.y *= s; v.z *= s; v.w *= s;
                }
            }
            *(float4*)&sA[row][kc * 4] = v;
        }
        // stage B: 32 rows x NOUT contiguous in global; float4 bulk copy
        const float* Bp = (k0 < DIM_IN) ? (Wroot + (size_t)k0 * NOUT)
                                        : (Wrel + (size_t)(k0 - DIM_IN) * NOUT);
#pragma unroll
        for (int q = 0; q < (8 * NOUT) / 256; q++) {
            int i4 = t + q * 256;
            ((float4*)&sB[0][0])[i4] = ((const float4*)Bp)[i4];
        }
        __syncthreads();
#pragma unroll
        for (int k = 0; k < 32; k++) {
            float bv[NC];
#pragma unroll
            for (int c = 0; c < NC; c++) bv[c] = sB[k][tx + 32 * c];
#pragma unroll
            for (int m = 0; m < 8; m++) {
                float a = sA[ty + 8 * m][k];
#pragma unroll
                for (int c = 0; c < NC; c++) acc[m][c] += a * bv[c];
            }
        }
        __syncthreads();
    }
    float bv[NC];
#pragma unroll
    for (int c = 0; c < NC; c++) bv[c] = bias[tx + 32 * c];
#pragma unroll
    for (int m = 0; m < 8; m++) {
        int rowg = m0 + ty + 8 * m;
        if (rowg < N) {
#pragma unroll
            for (int c = 0; c < NC; c++) {
                float v = acc[m][c] + bv[c];
                if (RELU) v = fmaxf(v, 0.f);
                out[(size_t)rowg * NOUT + tx + 32 * c] = v;
            }
        }
    }
}

extern "C" void kernel_launch(void* const* d_in, const int* in_sizes, int n_in,
                              void* d_out, int out_size, void* d_ws, size_t ws_size,
                              hipStream_t stream) {
    const float* x = (const float*)d_in[0];
    const int* ei = (const int*)d_in[1];
    const int* et = (const int*)d_in[2];
    const float* Wroot1 = (const float*)d_in[3];
    const float* Wrel1 = (const float*)d_in[4];
    const float* b1 = (const float*)d_in[5];
    const float* Wroot2 = (const float*)d_in[6];
    const float* Wrel2 = (const float*)d_in[7];
    const float* b2 = (const float*)d_in[8];
    float* out = (float*)d_out;

    int N = in_sizes[0] / DIM_IN;
    int E = in_sizes[2];

    size_t aggElems = (size_t)N * NREL * DIM_IN;
    size_t hElems = (size_t)N * DIM_IN;
    size_t degElems = (size_t)N * NREL;
    size_t need = (aggElems + hElems + degElems) * sizeof(float);
    if (ws_size < need) return;  // clean failure signal if scratch too small

    float* agg = (float*)d_ws;
    float* h = agg + aggElems;
    float* deg = h + hElems;

    hipMemsetAsync(agg, 0, aggElems * sizeof(float), stream);
    hipMemsetAsync(deg, 0, degElems * sizeof(float), stream);
    deg_kernel<<<(E + 255) / 256, 256, 0, stream>>>(ei, et, deg, E);
    inv_kernel<<<((int)degElems + 255) / 256, 256, 0, stream>>>(deg, (int)degElems);
    scatter_kernel<<<(E + 7) / 8, 256, 0, stream>>>(x, ei, et, agg, E);
    int gB = (N + 63) / 64;
    gemm_kernel<128, true><<<gB, 256, 0, stream>>>(x, agg, deg, Wroot1, Wrel1, b1, h, N);
    hipMemsetAsync(agg, 0, aggElems * sizeof(float), stream);
    scatter_kernel<<<(E + 7) / 8, 256, 0, stream>>>(h, ei, et, agg, E);
    gemm_kernel<96, false><<<gB, 256, 0, stream>>>(h, agg, deg, Wroot2, Wrel2, b2, out, N);
}

// Round 2
// 543.549 us; speedup vs baseline: 4.5926x; 4.5926x over previous
//
#include <hip/hip_runtime.h>

#define DIM_IN 128
#define NREL 4
#define KTOT (DIM_IN + NREL * DIM_IN)  // 640
#define SCAN_CHUNK 1024

__device__ inline unsigned short f2bf(float f) {  // round-to-nearest-even bf16
    union { float f; unsigned int i; } c;
    c.f = f;
    unsigned int r = c.i + 0x7FFF + ((c.i >> 16) & 1);
    return (unsigned short)(r >> 16);
}
__device__ inline float bf2f(unsigned short u) {
    union { unsigned int i; float f; } c;
    c.i = ((unsigned int)u) << 16;
    return c.f;
}

// ---------------- CSR build ----------------
__global__ void count_kernel(const int* __restrict__ ei, const int* __restrict__ et,
                             int* __restrict__ counts, int E) {
    int e = blockIdx.x * 256 + threadIdx.x;
    if (e >= E) return;
    atomicAdd(&counts[(size_t)ei[E + e] * NREL + et[e]], 1);
}

__device__ int block_exscan256(int v) {  // exclusive scan over 256 threads
    __shared__ int tmp[256];
    int t = threadIdx.x;
    tmp[t] = v;
    __syncthreads();
    for (int d = 1; d < 256; d <<= 1) {
        int add = (t >= d) ? tmp[t - d] : 0;
        __syncthreads();
        tmp[t] += add;
        __syncthreads();
    }
    return tmp[t] - v;
}

__global__ __launch_bounds__(256) void scanA_kernel(const int* __restrict__ counts,
                                                    int* __restrict__ chunkTot, int nb) {
    int base = blockIdx.x * SCAN_CHUNK + threadIdx.x * 4;
    int s = 0;
#pragma unroll
    for (int i = 0; i < 4; i++) {
        int idx = base + i;
        s += (idx < nb) ? counts[idx] : 0;
    }
    __shared__ int red[256];
    red[threadIdx.x] = s;
    __syncthreads();
    for (int d = 128; d > 0; d >>= 1) {
        if (threadIdx.x < d) red[threadIdx.x] += red[threadIdx.x + d];
        __syncthreads();
    }
    if (threadIdx.x == 0) chunkTot[blockIdx.x] = red[0];
}

__global__ __launch_bounds__(256) void scanB_kernel(const int* __restrict__ chunkTot,
                                                    int* __restrict__ chunkBase, int nChunks) {
    int t = threadIdx.x;
    int v = (t < nChunks) ? chunkTot[t] : 0;
    int ex = block_exscan256(v);
    if (t < nChunks) chunkBase[t] = ex;
}

__global__ __launch_bounds__(256) void scanC_kernel(const int* __restrict__ counts,
                                                    const int* __restrict__ chunkBase,
                                                    int* __restrict__ offs,
                                                    int* __restrict__ cursor, int nb) {
    int base = blockIdx.x * SCAN_CHUNK + threadIdx.x * 4;
    int c[4], s = 0;
#pragma unroll
    for (int i = 0; i < 4; i++) {
        int idx = base + i;
        c[i] = (idx < nb) ? counts[idx] : 0;
        s += c[i];
    }
    int pos = block_exscan256(s) + chunkBase[blockIdx.x];
#pragma unroll
    for (int i = 0; i < 4; i++) {
        int idx = base + i;
        if (idx < nb) {
            offs[idx] = pos;
            cursor[idx] = pos;
        }
        pos += c[i];
    }
}

__global__ void place_kernel(const int* __restrict__ ei, const int* __restrict__ et,
                             int* __restrict__ cursor, int* __restrict__ csr, int E) {
    int e = blockIdx.x * 256 + threadIdx.x;
    if (e >= E) return;
    int b = ei[E + e] * NREL + et[e];
    int p = atomicAdd(&cursor[b], 1);
    csr[p] = ei[e];  // src
}

// ---------------- gather-aggregate: agg[g][:] = (1/cnt) * sum x[src][:] ----------------
// 8 groups of 32 lanes per block; group g handles bucket g = dst*NREL+rel.
__global__ __launch_bounds__(256) void agg_kernel(
    const float* __restrict__ feat, const int* __restrict__ csr,
    const int* __restrict__ offs, const int* __restrict__ counts,
    unsigned short* __restrict__ agg, int nb) {
    int lane = threadIdx.x & 31;
    int g = blockIdx.x * 8 + (threadIdx.x >> 5);
    if (g >= nb) return;
    int start = offs[g];
    int cnt = counts[g];
    float4 acc = make_float4(0.f, 0.f, 0.f, 0.f);
    for (int i = 0; i < cnt; i++) {
        int s = csr[start + i];
        float4 v = ((const float4*)(feat + (size_t)s * DIM_IN))[lane];
        acc.x += v.x; acc.y += v.y; acc.z += v.z; acc.w += v.w;
    }
    float sc = (cnt > 0) ? (1.0f / (float)cnt) : 0.f;
    ushort4 o;
    o.x = f2bf(acc.x * sc);
    o.y = f2bf(acc.y * sc);
    o.z = f2bf(acc.z * sc);
    o.w = f2bf(acc.w * sc);
    *(ushort4*)(agg + (size_t)g * DIM_IN + lane * 4) = o;
}

// ---------------- GEMM: out = [X | agg] @ [Wroot; Wrel] + bias ----------------
template <int NOUT, bool RELU>
__global__ __launch_bounds__(256) void gemm_kernel(
    const float* __restrict__ X,            // [N,128] fp32
    const unsigned short* __restrict__ agg, // [N,512] bf16 (already deg-normalized)
    const float* __restrict__ Wroot,        // [128,NOUT]
    const float* __restrict__ Wrel,         // [512,NOUT]
    const float* __restrict__ bias,         // [NOUT]
    float* __restrict__ out,                // [N,NOUT]
    int N) {
    constexpr int NC = NOUT / 32;
    __shared__ float sA[64][36];
    __shared__ float sB[32][NOUT];
    const int t = threadIdx.x;
    const int tx = t & 31, ty = t >> 5;
    const int m0 = blockIdx.x * 64;

    float acc[8][NC];
#pragma unroll
    for (int m = 0; m < 8; m++)
#pragma unroll
        for (int c = 0; c < NC; c++) acc[m][c] = 0.f;

    for (int k0 = 0; k0 < KTOT; k0 += 32) {
#pragma unroll
        for (int q = 0; q < 2; q++) {
            int idx4 = t + q * 256;
            int row = idx4 >> 3, kc = idx4 & 7;
            int rowg = m0 + row;
            float4 v = make_float4(0.f, 0.f, 0.f, 0.f);
            if (rowg < N) {
                if (k0 < DIM_IN) {
                    v = *(const float4*)(X + (size_t)rowg * DIM_IN + k0 + kc * 4);
                } else {
                    ushort4 u = *(const ushort4*)(agg + (size_t)rowg * (NREL * DIM_IN) +
                                                  (k0 - DIM_IN) + kc * 4);
                    v.x = bf2f(u.x); v.y = bf2f(u.y); v.z = bf2f(u.z); v.w = bf2f(u.w);
                }
            }
            *(float4*)&sA[row][kc * 4] = v;
        }
        const float* Bp = (k0 < DIM_IN) ? (Wroot + (size_t)k0 * NOUT)
                                        : (Wrel + (size_t)(k0 - DIM_IN) * NOUT);
#pragma unroll
        for (int q = 0; q < (8 * NOUT) / 256; q++) {
            int i4 = t + q * 256;
            ((float4*)&sB[0][0])[i4] = ((const float4*)Bp)[i4];
        }
        __syncthreads();
#pragma unroll
        for (int k = 0; k < 32; k++) {
            float bv[NC];
#pragma unroll
            for (int c = 0; c < NC; c++) bv[c] = sB[k][tx + 32 * c];
#pragma unroll
            for (int m = 0; m < 8; m++) {
                float a = sA[ty + 8 * m][k];
#pragma unroll
                for (int c = 0; c < NC; c++) acc[m][c] += a * bv[c];
            }
        }
        __syncthreads();
    }
    float bv[NC];
#pragma unroll
    for (int c = 0; c < NC; c++) bv[c] = bias[tx + 32 * c];
#pragma unroll
    for (int m = 0; m < 8; m++) {
        int rowg = m0 + ty + 8 * m;
        if (rowg < N) {
#pragma unroll
            for (int c = 0; c < NC; c++) {
                float v = acc[m][c] + bv[c];
                if (RELU) v = fmaxf(v, 0.f);
                out[(size_t)rowg * NOUT + tx + 32 * c] = v;
            }
        }
    }
}

extern "C" void kernel_launch(void* const* d_in, const int* in_sizes, int n_in,
                              void* d_out, int out_size, void* d_ws, size_t ws_size,
                              hipStream_t stream) {
    const float* x = (const float*)d_in[0];
    const int* ei = (const int*)d_in[1];
    const int* et = (const int*)d_in[2];
    const float* Wroot1 = (const float*)d_in[3];
    const float* Wrel1 = (const float*)d_in[4];
    const float* b1 = (const float*)d_in[5];
    const float* Wroot2 = (const float*)d_in[6];
    const float* Wrel2 = (const float*)d_in[7];
    const float* b2 = (const float*)d_in[8];
    float* out = (float*)d_out;

    int N = in_sizes[0] / DIM_IN;
    int E = in_sizes[2];
    int nb = N * NREL;
    int nChunks = (nb + SCAN_CHUNK - 1) / SCAN_CHUNK;  // 196 for N=50000

    // workspace layout (all 16B aligned)
    char* p = (char*)d_ws;
    unsigned short* agg = (unsigned short*)p;       p += (size_t)nb * DIM_IN * sizeof(unsigned short);
    float* h = (float*)p;                           p += (size_t)N * DIM_IN * sizeof(float);
    int* counts = (int*)p;                          p += (size_t)nb * sizeof(int);
    int* offs = (int*)p;                            p += (size_t)nb * sizeof(int);
    int* cursor = (int*)p;                          p += (size_t)nb * sizeof(int);
    int* chunkTot = (int*)p;                        p += 256 * sizeof(int);
    int* chunkBase = (int*)p;                       p += 256 * sizeof(int);
    int* csr = (int*)p;                             p += (size_t)E * sizeof(int);
    if ((size_t)(p - (char*)d_ws) > ws_size) return;

    // ---- CSR build (graph-only; shared by both layers) ----
    hipMemsetAsync(counts, 0, (size_t)nb * sizeof(int), stream);
    count_kernel<<<(E + 255) / 256, 256, 0, stream>>>(ei, et, counts, E);
    scanA_kernel<<<nChunks, 256, 0, stream>>>(counts, chunkTot, nb);
    scanB_kernel<<<1, 256, 0, stream>>>(chunkTot, chunkBase, nChunks);
    scanC_kernel<<<nChunks, 256, 0, stream>>>(counts, chunkBase, offs, cursor, nb);
    place_kernel<<<(E + 255) / 256, 256, 0, stream>>>(ei, et, cursor, csr, E);

    int gAgg = (nb + 7) / 8;
    int gB = (N + 63) / 64;
    // ---- layer 1 ----
    agg_kernel<<<gAgg, 256, 0, stream>>>(x, csr, offs, counts, agg, nb);
    gemm_kernel<128, true><<<gB, 256, 0, stream>>>(x, agg, Wroot1, Wrel1, b1, h, N);
    // ---- layer 2 ----
    agg_kernel<<<gAgg, 256, 0, stream>>>(h, csr, offs, counts, agg, nb);
    gemm_kernel<96, false><<<gB, 256, 0, stream>>>(h, agg, Wroot2, Wrel2, b2, out, N);
}

// Round 3
// 377.769 us; speedup vs baseline: 6.6080x; 1.4388x over previous
//
#include <hip/hip_runtime.h>

#define DIM_IN 128
#define NREL 4
#define KTOT (DIM_IN + NREL * DIM_IN)  // 640
#define SCAN_CHUNK 1024

typedef __attribute__((ext_vector_type(8))) short short8;
typedef __attribute__((ext_vector_type(4))) float floatx4;

__device__ inline unsigned short f2bf(float f) {  // round-to-nearest-even bf16
    union { float f; unsigned int i; } c;
    c.f = f;
    unsigned int r = c.i + 0x7FFF + ((c.i >> 16) & 1);
    return (unsigned short)(r >> 16);
}
__device__ inline float bf2f(unsigned short u) {
    union { unsigned int i; float f; } c;
    c.i = ((unsigned int)u) << 16;
    return c.f;
}

// ---------------- CSR build ----------------
__global__ void count_kernel(const int* __restrict__ ei, const int* __restrict__ et,
                             int* __restrict__ counts, int E) {
    int e = blockIdx.x * 256 + threadIdx.x;
    if (e >= E) return;
    atomicAdd(&counts[(size_t)ei[E + e] * NREL + et[e]], 1);
}

__device__ int block_exscan256(int v) {
    __shared__ int tmp[256];
    int t = threadIdx.x;
    tmp[t] = v;
    __syncthreads();
    for (int d = 1; d < 256; d <<= 1) {
        int add = (t >= d) ? tmp[t - d] : 0;
        __syncthreads();
        tmp[t] += add;
        __syncthreads();
    }
    return tmp[t] - v;
}

__global__ __launch_bounds__(256) void scanA_kernel(const int* __restrict__ counts,
                                                    int* __restrict__ chunkTot, int nb) {
    int base = blockIdx.x * SCAN_CHUNK + threadIdx.x * 4;
    int s = 0;
#pragma unroll
    for (int i = 0; i < 4; i++) {
        int idx = base + i;
        s += (idx < nb) ? counts[idx] : 0;
    }
    __shared__ int red[256];
    red[threadIdx.x] = s;
    __syncthreads();
    for (int d = 128; d > 0; d >>= 1) {
        if (threadIdx.x < d) red[threadIdx.x] += red[threadIdx.x + d];
        __syncthreads();
    }
    if (threadIdx.x == 0) chunkTot[blockIdx.x] = red[0];
}

__global__ __launch_bounds__(256) void scanB_kernel(const int* __restrict__ chunkTot,
                                                    int* __restrict__ chunkBase, int nChunks) {
    int t = threadIdx.x;
    int v = (t < nChunks) ? chunkTot[t] : 0;
    int ex = block_exscan256(v);
    if (t < nChunks) chunkBase[t] = ex;
}

__global__ __launch_bounds__(256) void scanC_kernel(const int* __restrict__ counts,
                                                    const int* __restrict__ chunkBase,
                                                    int* __restrict__ offs,
                                                    int* __restrict__ cursor, int nb) {
    int base = blockIdx.x * SCAN_CHUNK + threadIdx.x * 4;
    int c[4], s = 0;
#pragma unroll
    for (int i = 0; i < 4; i++) {
        int idx = base + i;
        c[i] = (idx < nb) ? counts[idx] : 0;
        s += c[i];
    }
    int pos = block_exscan256(s) + chunkBase[blockIdx.x];
#pragma unroll
    for (int i = 0; i < 4; i++) {
        int idx = base + i;
        if (idx < nb) {
            offs[idx] = pos;
            cursor[idx] = pos;
        }
        pos += c[i];
    }
}

__global__ void place_kernel(const int* __restrict__ ei, const int* __restrict__ et,
                             int* __restrict__ cursor, int* __restrict__ csr, int E) {
    int e = blockIdx.x * 256 + threadIdx.x;
    if (e >= E) return;
    int b = ei[E + e] * NREL + et[e];
    int p = atomicAdd(&cursor[b], 1);
    csr[p] = ei[e];
}

// ---------------- conversions ----------------
__global__ void cvt_x_kernel(const float* __restrict__ x, unsigned short* __restrict__ xb,
                             int n4) {  // n4 = total/4
    int i = blockIdx.x * 256 + threadIdx.x;
    if (i >= n4) return;
    float4 v = ((const float4*)x)[i];
    ushort4 o;
    o.x = f2bf(v.x); o.y = f2bf(v.y); o.z = f2bf(v.z); o.w = f2bf(v.w);
    ((ushort4*)xb)[i] = o;
}

// Wt[n][k] = W[k][n], bf16. W = [Wroot(128 rows); Wrel(512 rows)], each row NOUT wide.
template <int NOUT>
__global__ void cvt_w_kernel(const float* __restrict__ Wroot, const float* __restrict__ Wrel,
                             unsigned short* __restrict__ Wt) {
    int t = blockIdx.x * 256 + threadIdx.x;
    if (t >= NOUT * KTOT) return;
    int n = t / KTOT, k = t - n * KTOT;
    float v = (k < DIM_IN) ? Wroot[(size_t)k * NOUT + n]
                           : Wrel[(size_t)(k - DIM_IN) * NOUT + n];
    Wt[t] = f2bf(v);
}

// ---------------- gather-aggregate (one wave64 per bucket) ----------------
// agg[g][:] = (1/cnt) * sum_{i} feat[csr[i]][:]   (bf16 in, fp32 accum, bf16 out)
__global__ __launch_bounds__(256) void agg_kernel(
    const unsigned short* __restrict__ feat, const int* __restrict__ csr,
    const int* __restrict__ offs, const int* __restrict__ counts,
    unsigned short* __restrict__ agg, int nb) {
    int lane = threadIdx.x & 63;
    int half = lane >> 5;       // two halves process alternate edges
    int col = lane & 31;        // 32 lanes x ushort4 = 128 bf16 row
    int g = blockIdx.x * 4 + (threadIdx.x >> 6);
    if (g >= nb) return;
    int start = offs[g];
    int cnt = counts[g];
    float4 acc = make_float4(0.f, 0.f, 0.f, 0.f);
    int i = half;
    for (; i + 2 < cnt; i += 4) {  // 2 rows in flight per half (4 per wave)
        int s0 = csr[start + i];
        int s1 = csr[start + i + 2];
        ushort4 u0 = *(const ushort4*)(feat + (size_t)s0 * DIM_IN + col * 4);
        ushort4 u1 = *(const ushort4*)(feat + (size_t)s1 * DIM_IN + col * 4);
        acc.x += bf2f(u0.x) + bf2f(u1.x);
        acc.y += bf2f(u0.y) + bf2f(u1.y);
        acc.z += bf2f(u0.z) + bf2f(u1.z);
        acc.w += bf2f(u0.w) + bf2f(u1.w);
    }
    for (; i < cnt; i += 2) {
        int s0 = csr[start + i];
        ushort4 u0 = *(const ushort4*)(feat + (size_t)s0 * DIM_IN + col * 4);
        acc.x += bf2f(u0.x);
        acc.y += bf2f(u0.y);
        acc.z += bf2f(u0.z);
        acc.w += bf2f(u0.w);
    }
    acc.x += __shfl_xor(acc.x, 32);
    acc.y += __shfl_xor(acc.y, 32);
    acc.z += __shfl_xor(acc.z, 32);
    acc.w += __shfl_xor(acc.w, 32);
    if (half == 0) {
        float sc = (cnt > 0) ? (1.0f / (float)cnt) : 0.f;
        ushort4 o;
        o.x = f2bf(acc.x * sc);
        o.y = f2bf(acc.y * sc);
        o.z = f2bf(acc.z * sc);
        o.w = f2bf(acc.w * sc);
        *(ushort4*)(agg + (size_t)g * DIM_IN + col * 4) = o;
    }
}

// ---------------- MFMA GEMM: out = [xb | agg] @ Wt^T + bias ----------------
// BM=64 per block (4 waves, each 32 rows x NOUT/2 cols). No LDS, no barriers:
// A and B fragments are direct 16B global loads (A[m=lane&15][k=quad*8+j];
// B via Wt[n][k] rows so b_frag is also contiguous). K=640 fully unrolled.
template <int NOUT, bool STORE_BF16_RELU>
__global__ __launch_bounds__(256) void mfma_gemm_kernel(
    const unsigned short* __restrict__ xb,   // [N,128] bf16
    const unsigned short* __restrict__ agg,  // [N,512] bf16 (normalized)
    const unsigned short* __restrict__ Wt,   // [NOUT,640] bf16 (transposed)
    const float* __restrict__ bias,          // [NOUT]
    void* __restrict__ outp,                 // bf16 [N,128] or f32 [N,NOUT]
    int N) {
    constexpr int NT = NOUT / 32;  // n-tiles per wave (4 or 3)
    const int lane = threadIdx.x & 63;
    const int w = threadIdx.x >> 6;
    const int mh = w >> 1, nh = w & 1;
    const int q = lane >> 4;        // quad 0..3
    const int l15 = lane & 15;
    const int m0 = blockIdx.x * 64 + mh * 32;
    const int ncol0 = nh * (NOUT / 2);

    floatx4 acc[2][NT];
#pragma unroll
    for (int mt = 0; mt < 2; mt++)
#pragma unroll
        for (int nt = 0; nt < NT; nt++) acc[mt][nt] = (floatx4)0.f;

    // clamped row indices for the two m-tiles (OOB rows masked at store)
    int row0 = m0 + l15;       if (row0 >= N) row0 = N - 1;
    int row1 = m0 + 16 + l15;  if (row1 >= N) row1 = N - 1;
    const unsigned short* wbase = Wt + (size_t)(ncol0 + l15) * KTOT + q * 8;

#pragma unroll
    for (int ks = 0; ks < KTOT / 32; ks++) {
        const int k0 = ks * 32;
        short8 a0, a1;
        if (k0 < DIM_IN) {
            a0 = *(const short8*)(xb + (size_t)row0 * DIM_IN + k0 + q * 8);
            a1 = *(const short8*)(xb + (size_t)row1 * DIM_IN + k0 + q * 8);
        } else {
            a0 = *(const short8*)(agg + (size_t)row0 * (NREL * DIM_IN) + (k0 - DIM_IN) + q * 8);
            a1 = *(const short8*)(agg + (size_t)row1 * (NREL * DIM_IN) + (k0 - DIM_IN) + q * 8);
        }
        short8 b[NT];
#pragma unroll
        for (int nt = 0; nt < NT; nt++)
            b[nt] = *(const short8*)(wbase + (size_t)nt * 16 * KTOT + k0);
#pragma unroll
        for (int nt = 0; nt < NT; nt++) {
            acc[0][nt] = __builtin_amdgcn_mfma_f32_16x16x32_bf16(a0, b[nt], acc[0][nt], 0, 0, 0);
            acc[1][nt] = __builtin_amdgcn_mfma_f32_16x16x32_bf16(a1, b[nt], acc[1][nt], 0, 0, 0);
        }
    }

    // epilogue: C/D layout col=lane&15, row=quad*4+reg
#pragma unroll
    for (int nt = 0; nt < NT; nt++) {
        int colg = ncol0 + nt * 16 + l15;
        float bv = bias[colg];
#pragma unroll
        for (int mt = 0; mt < 2; mt++) {
            int rbase = m0 + mt * 16 + q * 4;
#pragma unroll
            for (int r = 0; r < 4; r++) {
                int grow = rbase + r;
                if (grow < N) {
                    float v = acc[mt][nt][r] + bv;
                    if (STORE_BF16_RELU) {
                        v = fmaxf(v, 0.f);
                        ((unsigned short*)outp)[(size_t)grow * NOUT + colg] = f2bf(v);
                    } else {
                        ((float*)outp)[(size_t)grow * NOUT + colg] = v;
                    }
                }
            }
        }
    }
}

extern "C" void kernel_launch(void* const* d_in, const int* in_sizes, int n_in,
                              void* d_out, int out_size, void* d_ws, size_t ws_size,
                              hipStream_t stream) {
    const float* x = (const float*)d_in[0];
    const int* ei = (const int*)d_in[1];
    const int* et = (const int*)d_in[2];
    const float* Wroot1 = (const float*)d_in[3];
    const float* Wrel1 = (const float*)d_in[4];
    const float* b1 = (const float*)d_in[5];
    const float* Wroot2 = (const float*)d_in[6];
    const float* Wrel2 = (const float*)d_in[7];
    const float* b2 = (const float*)d_in[8];
    float* out = (float*)d_out;

    int N = in_sizes[0] / DIM_IN;
    int E = in_sizes[2];
    int nb = N * NREL;
    int nChunks = (nb + SCAN_CHUNK - 1) / SCAN_CHUNK;

    // workspace layout (16B-aligned chunks first)
    char* p = (char*)d_ws;
    unsigned short* xb = (unsigned short*)p;   p += (size_t)N * DIM_IN * 2;
    unsigned short* hb = (unsigned short*)p;   p += (size_t)N * DIM_IN * 2;
    unsigned short* agg = (unsigned short*)p;  p += (size_t)nb * DIM_IN * 2;
    unsigned short* Wt1 = (unsigned short*)p;  p += (size_t)128 * KTOT * 2;
    unsigned short* Wt2 = (unsigned short*)p;  p += (size_t)96 * KTOT * 2;
    int* counts = (int*)p;                     p += (size_t)nb * 4;
    int* offs = (int*)p;                       p += (size_t)nb * 4;
    int* cursor = (int*)p;                     p += (size_t)nb * 4;
    int* chunkTot = (int*)p;                   p += 256 * 4;
    int* chunkBase = (int*)p;                  p += 256 * 4;
    int* csr = (int*)p;                        p += (size_t)E * 4;
    if ((size_t)(p - (char*)d_ws) > ws_size) return;

    // ---- CSR build ----
    hipMemsetAsync(counts, 0, (size_t)nb * sizeof(int), stream);
    count_kernel<<<(E + 255) / 256, 256, 0, stream>>>(ei, et, counts, E);
    scanA_kernel<<<nChunks, 256, 0, stream>>>(counts, chunkTot, nb);
    scanB_kernel<<<1, 256, 0, stream>>>(chunkTot, chunkBase, nChunks);
    scanC_kernel<<<nChunks, 256, 0, stream>>>(counts, chunkBase, offs, cursor, nb);
    place_kernel<<<(E + 255) / 256, 256, 0, stream>>>(ei, et, cursor, csr, E);

    // ---- conversions ----
    int n4 = N * DIM_IN / 4;
    cvt_x_kernel<<<(n4 + 255) / 256, 256, 0, stream>>>(x, xb, n4);
    cvt_w_kernel<128><<<(128 * KTOT + 255) / 256, 256, 0, stream>>>(Wroot1, Wrel1, Wt1);
    cvt_w_kernel<96><<<(96 * KTOT + 255) / 256, 256, 0, stream>>>(Wroot2, Wrel2, Wt2);

    int gAgg = (nb + 3) / 4;
    int gB = (N + 63) / 64;
    // ---- layer 1 ----
    agg_kernel<<<gAgg, 256, 0, stream>>>(xb, csr, offs, counts, agg, nb);
    mfma_gemm_kernel<128, true><<<gB, 256, 0, stream>>>(xb, agg, Wt1, b1, hb, N);
    // ---- layer 2 ----
    agg_kernel<<<gAgg, 256, 0, stream>>>(hb, csr, offs, counts, agg, nb);
    mfma_gemm_kernel<96, false><<<gB, 256, 0, stream>>>(hb, agg, Wt2, b2, out, N);
}

// Round 4
// 269.911 us; speedup vs baseline: 9.2486x; 1.3996x over previous
//
#include <hip/hip_runtime.h>

#define DIM_IN 128
#define NREL 4
#define KTOT (DIM_IN + NREL * DIM_IN)  // 640
#define SCAN_CHUNK 1024

typedef __attribute__((ext_vector_type(8))) short short8;
typedef __attribute__((ext_vector_type(4))) float floatx4;

__device__ inline unsigned short f2bf(float f) {  // round-to-nearest-even bf16
    union { float f; unsigned int i; } c;
    c.f = f;
    unsigned int r = c.i + 0x7FFF + ((c.i >> 16) & 1);
    return (unsigned short)(r >> 16);
}
__device__ inline float bf2f(unsigned short u) {
    union { unsigned int i; float f; } c;
    c.i = ((unsigned int)u) << 16;
    return c.f;
}

__device__ inline void gload16_lds(const void* g, void* l) {
    __builtin_amdgcn_global_load_lds((const __attribute__((address_space(1))) unsigned int*)g,
                                     (__attribute__((address_space(3))) unsigned int*)l,
                                     16, 0, 0);
}

// ---------------- CSR build ----------------
__global__ void count_kernel(const int* __restrict__ ei, const int* __restrict__ et,
                             int* __restrict__ counts, int E) {
    int e = blockIdx.x * 256 + threadIdx.x;
    if (e >= E) return;
    atomicAdd(&counts[(size_t)ei[E + e] * NREL + et[e]], 1);
}

__device__ int block_exscan256(int v) {
    __shared__ int tmp[256];
    int t = threadIdx.x;
    tmp[t] = v;
    __syncthreads();
    for (int d = 1; d < 256; d <<= 1) {
        int add = (t >= d) ? tmp[t - d] : 0;
        __syncthreads();
        tmp[t] += add;
        __syncthreads();
    }
    return tmp[t] - v;
}

__global__ __launch_bounds__(256) void scanA_kernel(const int* __restrict__ counts,
                                                    int* __restrict__ chunkTot, int nb) {
    int base = blockIdx.x * SCAN_CHUNK + threadIdx.x * 4;
    int s = 0;
#pragma unroll
    for (int i = 0; i < 4; i++) {
        int idx = base + i;
        s += (idx < nb) ? counts[idx] : 0;
    }
    __shared__ int red[256];
    red[threadIdx.x] = s;
    __syncthreads();
    for (int d = 128; d > 0; d >>= 1) {
        if (threadIdx.x < d) red[threadIdx.x] += red[threadIdx.x + d];
        __syncthreads();
    }
    if (threadIdx.x == 0) chunkTot[blockIdx.x] = red[0];
}

__global__ __launch_bounds__(256) void scanB_kernel(const int* __restrict__ chunkTot,
                                                    int* __restrict__ chunkBase, int nChunks) {
    int t = threadIdx.x;
    int v = (t < nChunks) ? chunkTot[t] : 0;
    int ex = block_exscan256(v);
    if (t < nChunks) chunkBase[t] = ex;
}

__global__ __launch_bounds__(256) void scanC_kernel(const int* __restrict__ counts,
                                                    const int* __restrict__ chunkBase,
                                                    int* __restrict__ offs,
                                                    int* __restrict__ cursor, int nb) {
    int base = blockIdx.x * SCAN_CHUNK + threadIdx.x * 4;
    int c[4], s = 0;
#pragma unroll
    for (int i = 0; i < 4; i++) {
        int idx = base + i;
        c[i] = (idx < nb) ? counts[idx] : 0;
        s += c[i];
    }
    int pos = block_exscan256(s) + chunkBase[blockIdx.x];
#pragma unroll
    for (int i = 0; i < 4; i++) {
        int idx = base + i;
        if (idx < nb) {
            offs[idx] = pos;
            cursor[idx] = pos;
        }
        pos += c[i];
    }
}

__global__ void place_kernel(const int* __restrict__ ei, const int* __restrict__ et,
                             int* __restrict__ cursor, int* __restrict__ csr, int E) {
    int e = blockIdx.x * 256 + threadIdx.x;
    if (e >= E) return;
    int b = ei[E + e] * NREL + et[e];
    int p = atomicAdd(&cursor[b], 1);
    csr[p] = ei[e];
}

// ---------------- conversions ----------------
__global__ void cvt_x_kernel(const float* __restrict__ x, unsigned short* __restrict__ xb,
                             int n4) {
    int i = blockIdx.x * 256 + threadIdx.x;
    if (i >= n4) return;
    float4 v = ((const float4*)x)[i];
    ushort4 o;
    o.x = f2bf(v.x); o.y = f2bf(v.y); o.z = f2bf(v.z); o.w = f2bf(v.w);
    ((ushort4*)xb)[i] = o;
}

// Wt[n][k] = W[k][n], bf16.
template <int NOUT>
__global__ void cvt_w_kernel(const float* __restrict__ Wroot, const float* __restrict__ Wrel,
                             unsigned short* __restrict__ Wt) {
    int t = blockIdx.x * 256 + threadIdx.x;
    if (t >= NOUT * KTOT) return;
    int n = t / KTOT, k = t - n * KTOT;
    float v = (k < DIM_IN) ? Wroot[(size_t)k * NOUT + n]
                           : Wrel[(size_t)(k - DIM_IN) * NOUT + n];
    Wt[t] = f2bf(v);
}

// ---------------- gather-aggregate: 16 lanes per bucket, 4 buckets/wave ----------------
__global__ __launch_bounds__(256) void agg_kernel(
    const unsigned short* __restrict__ feat, const int* __restrict__ csr,
    const int* __restrict__ offs, const int* __restrict__ counts,
    unsigned short* __restrict__ agg, int nb) {
    int l16 = threadIdx.x & 15;
    int g = (blockIdx.x * 256 + threadIdx.x) >> 4;
    if (g >= nb) return;
    int start = offs[g];
    int cnt = counts[g];
    float acc[8];
#pragma unroll
    for (int j = 0; j < 8; j++) acc[j] = 0.f;
    int i = 0;
    for (; i + 1 < cnt; i += 2) {  // 2 gathers in flight per group
        int s0 = csr[start + i];
        int s1 = csr[start + i + 1];
        short8 u0 = *(const short8*)(feat + (size_t)s0 * DIM_IN + l16 * 8);
        short8 u1 = *(const short8*)(feat + (size_t)s1 * DIM_IN + l16 * 8);
#pragma unroll
        for (int j = 0; j < 8; j++)
            acc[j] += bf2f((unsigned short)u0[j]) + bf2f((unsigned short)u1[j]);
    }
    if (i < cnt) {
        int s0 = csr[start + i];
        short8 u0 = *(const short8*)(feat + (size_t)s0 * DIM_IN + l16 * 8);
#pragma unroll
        for (int j = 0; j < 8; j++) acc[j] += bf2f((unsigned short)u0[j]);
    }
    float sc = (cnt > 0) ? (1.0f / (float)cnt) : 0.f;
    short8 o;
#pragma unroll
    for (int j = 0; j < 8; j++) o[j] = (short)f2bf(acc[j] * sc);
    *(short8*)(agg + (size_t)g * DIM_IN + l16 * 8) = o;
}

// ---------------- MFMA GEMM, m97 structure ----------------
// BM=128, BN=NOUT, BK=32. 4 waves: wave (wm,wn) computes 64 rows x NOUT/2 cols.
// A,B staged to LDS via global_load_lds width=16; frags via ds_read_b128.
template <int NOUT, bool STORE_BF16_RELU>
__global__ __launch_bounds__(256) void mfma_gemm_kernel(
    const unsigned short* __restrict__ xb,   // [N,128] bf16
    const unsigned short* __restrict__ agg,  // [N,512] bf16 (normalized)
    const unsigned short* __restrict__ Wt,   // [NOUT,640] bf16 (transposed)
    const float* __restrict__ bias,          // [NOUT]
    void* __restrict__ outp,                 // bf16 [N,128] or f32 [N,NOUT]
    int N) {
    constexpr int NT = NOUT / 32;       // n-tiles per wave (4 or 3)
    constexpr int BCHUNKS = NOUT * 4;   // 16B chunks in B tile
    __shared__ unsigned short sA[128 * 32];
    __shared__ unsigned short sB[NOUT * 32];
    const int t = threadIdx.x;
    const int w = t >> 6;
    const int lane = t & 63;
    const int q = lane >> 4;
    const int l15 = lane & 15;
    const int wm = w >> 1, wn = w & 1;
    const int m0 = blockIdx.x * 128;

    floatx4 acc[4][NT];
#pragma unroll
    for (int mt = 0; mt < 4; mt++)
#pragma unroll
        for (int nt = 0; nt < NT; nt++) acc[mt][nt] = (floatx4)0.f;

    for (int ks = 0; ks < KTOT / 32; ks++) {
        const int k0 = ks * 32;
        // ---- stage A: 128 rows x 32 k = 512 chunks of 16B ----
#pragma unroll
        for (int r = 0; r < 2; r++) {
            int idx = t + r * 256;
            int row = idx >> 2, ch = idx & 3;
            int rowg = m0 + row;
            if (rowg >= N) rowg = N - 1;
            const unsigned short* gp =
                (k0 < DIM_IN)
                    ? (xb + (size_t)rowg * DIM_IN + k0 + ch * 8)
                    : (agg + (size_t)rowg * (NREL * DIM_IN) + (k0 - DIM_IN) + ch * 8);
            gload16_lds(gp, sA + (size_t)(r * 256 + w * 64) * 8);
        }
        // ---- stage B: NOUT rows x 32 k ----
#pragma unroll
        for (int r = 0; r < (BCHUNKS + 255) / 256; r++) {
            if (r * 256 + w * 64 < BCHUNKS) {  // wave-uniform guard
                int idx = t + r * 256;
                int nrow = idx >> 2, ch = idx & 3;
                const unsigned short* gp = Wt + (size_t)nrow * KTOT + k0 + ch * 8;
                gload16_lds(gp, sB + (size_t)(r * 256 + w * 64) * 8);
            }
        }
        __syncthreads();
        // ---- fragments + MFMA ----
        short8 aF[4], bF[NT];
#pragma unroll
        for (int mt = 0; mt < 4; mt++)
            aF[mt] = *(const short8*)(sA + (size_t)(wm * 64 + mt * 16 + l15) * 32 + q * 8);
#pragma unroll
        for (int nt = 0; nt < NT; nt++)
            bF[nt] = *(const short8*)(sB + (size_t)(wn * (NOUT / 2) + nt * 16 + l15) * 32 + q * 8);
#pragma unroll
        for (int mt = 0; mt < 4; mt++)
#pragma unroll
            for (int nt = 0; nt < NT; nt++)
                acc[mt][nt] =
                    __builtin_amdgcn_mfma_f32_16x16x32_bf16(aF[mt], bF[nt], acc[mt][nt], 0, 0, 0);
        __syncthreads();
    }

    // epilogue: C/D layout col=lane&15, row=quad*4+reg
#pragma unroll
    for (int nt = 0; nt < NT; nt++) {
        int colg = wn * (NOUT / 2) + nt * 16 + l15;
        float bv = bias[colg];
#pragma unroll
        for (int mt = 0; mt < 4; mt++) {
            int rbase = m0 + wm * 64 + mt * 16 + q * 4;
#pragma unroll
            for (int r = 0; r < 4; r++) {
                int grow = rbase + r;
                if (grow < N) {
                    float v = acc[mt][nt][r] + bv;
                    if (STORE_BF16_RELU) {
                        v = fmaxf(v, 0.f);
                        ((unsigned short*)outp)[(size_t)grow * NOUT + colg] = f2bf(v);
                    } else {
                        ((float*)outp)[(size_t)grow * NOUT + colg] = v;
                    }
                }
            }
        }
    }
}

extern "C" void kernel_launch(void* const* d_in, const int* in_sizes, int n_in,
                              void* d_out, int out_size, void* d_ws, size_t ws_size,
                              hipStream_t stream) {
    const float* x = (const float*)d_in[0];
    const int* ei = (const int*)d_in[1];
    const int* et = (const int*)d_in[2];
    const float* Wroot1 = (const float*)d_in[3];
    const float* Wrel1 = (const float*)d_in[4];
    const float* b1 = (const float*)d_in[5];
    const float* Wroot2 = (const float*)d_in[6];
    const float* Wrel2 = (const float*)d_in[7];
    const float* b2 = (const float*)d_in[8];
    float* out = (float*)d_out;

    int N = in_sizes[0] / DIM_IN;
    int E = in_sizes[2];
    int nb = N * NREL;
    int nChunks = (nb + SCAN_CHUNK - 1) / SCAN_CHUNK;

    char* p = (char*)d_ws;
    unsigned short* xb = (unsigned short*)p;   p += (size_t)N * DIM_IN * 2;
    unsigned short* hb = (unsigned short*)p;   p += (size_t)N * DIM_IN * 2;
    unsigned short* agg = (unsigned short*)p;  p += (size_t)nb * DIM_IN * 2;
    unsigned short* Wt1 = (unsigned short*)p;  p += (size_t)128 * KTOT * 2;
    unsigned short* Wt2 = (unsigned short*)p;  p += (size_t)96 * KTOT * 2;
    int* counts = (int*)p;                     p += (size_t)nb * 4;
    int* offs = (int*)p;                       p += (size_t)nb * 4;
    int* cursor = (int*)p;                     p += (size_t)nb * 4;
    int* chunkTot = (int*)p;                   p += 256 * 4;
    int* chunkBase = (int*)p;                  p += 256 * 4;
    int* csr = (int*)p;                        p += (size_t)E * 4;
    if ((size_t)(p - (char*)d_ws) > ws_size) return;

    // ---- CSR build ----
    hipMemsetAsync(counts, 0, (size_t)nb * sizeof(int), stream);
    count_kernel<<<(E + 255) / 256, 256, 0, stream>>>(ei, et, counts, E);
    scanA_kernel<<<nChunks, 256, 0, stream>>>(counts, chunkTot, nb);
    scanB_kernel<<<1, 256, 0, stream>>>(chunkTot, chunkBase, nChunks);
    scanC_kernel<<<nChunks, 256, 0, stream>>>(counts, chunkBase, offs, cursor, nb);
    place_kernel<<<(E + 255) / 256, 256, 0, stream>>>(ei, et, cursor, csr, E);

    // ---- conversions ----
    int n4 = N * DIM_IN / 4;
    cvt_x_kernel<<<(n4 + 255) / 256, 256, 0, stream>>>(x, xb, n4);
    cvt_w_kernel<128><<<(128 * KTOT + 255) / 256, 256, 0, stream>>>(Wroot1, Wrel1, Wt1);
    cvt_w_kernel<96><<<(96 * KTOT + 255) / 256, 256, 0, stream>>>(Wroot2, Wrel2, Wt2);

    int gAgg = (nb * 16 + 255) / 256;
    int gB = (N + 127) / 128;
    // ---- layer 1 ----
    agg_kernel<<<gAgg, 256, 0, stream>>>(xb, csr, offs, counts, agg, nb);
    mfma_gemm_kernel<128, true><<<gB, 256, 0, stream>>>(xb, agg, Wt1, b1, hb, N);
    // ---- layer 2 ----
    agg_kernel<<<gAgg, 256, 0, stream>>>(hb, csr, offs, counts, agg, nb);
    mfma_gemm_kernel<96, false><<<gB, 256, 0, stream>>>(hb, agg, Wt2, b2, out, N);
}

// Round 5
// 262.258 us; speedup vs baseline: 9.5185x; 1.0292x over previous
//
#include <hip/hip_runtime.h>

#define DIM_IN 128
#define NREL 4
#define KTOT (DIM_IN + NREL * DIM_IN)  // 640
#define SCAN_CHUNK 1024

typedef __attribute__((ext_vector_type(8))) short short8;
typedef __attribute__((ext_vector_type(4))) float floatx4;

__device__ inline unsigned short f2bf(float f) {  // round-to-nearest-even bf16
    union { float f; unsigned int i; } c;
    c.f = f;
    unsigned int r = c.i + 0x7FFF + ((c.i >> 16) & 1);
    return (unsigned short)(r >> 16);
}
__device__ inline float bf2f(unsigned short u) {
    union { unsigned int i; float f; } c;
    c.i = ((unsigned int)u) << 16;
    return c.f;
}

__device__ inline void gload16_lds(const void* g, void* l) {
    __builtin_amdgcn_global_load_lds((const __attribute__((address_space(1))) unsigned int*)g,
                                     (__attribute__((address_space(3))) unsigned int*)l,
                                     16, 0, 0);
}

// ---------------- fused prep: cvt_x + cvt_w1 + cvt_w2 + count ----------------
__global__ __launch_bounds__(256) void prep_kernel(
    const float* __restrict__ x, unsigned short* __restrict__ xb, int n4,
    const float* __restrict__ Wroot1, const float* __restrict__ Wrel1,
    unsigned short* __restrict__ Wt1,
    const float* __restrict__ Wroot2, const float* __restrict__ Wrel2,
    unsigned short* __restrict__ Wt2,
    const int* __restrict__ ei, const int* __restrict__ et,
    int* __restrict__ counts, int E) {
    int t = blockIdx.x * 256 + threadIdx.x;
    if (t < n4) {
        float4 v = ((const float4*)x)[t];
        ushort4 o;
        o.x = f2bf(v.x); o.y = f2bf(v.y); o.z = f2bf(v.z); o.w = f2bf(v.w);
        ((ushort4*)xb)[t] = o;
    }
    if (t < (128 + 96) * KTOT) {
        if (t < 128 * KTOT) {
            int n = t / KTOT, k = t - n * KTOT;
            float v = (k < DIM_IN) ? Wroot1[(size_t)k * 128 + n]
                                   : Wrel1[(size_t)(k - DIM_IN) * 128 + n];
            Wt1[t] = f2bf(v);
        } else {
            int t2 = t - 128 * KTOT;
            int n = t2 / KTOT, k = t2 - n * KTOT;
            float v = (k < DIM_IN) ? Wroot2[(size_t)k * 96 + n]
                                   : Wrel2[(size_t)(k - DIM_IN) * 96 + n];
            Wt2[t2] = f2bf(v);
        }
    }
    if (t < E) {
        atomicAdd(&counts[(size_t)ei[E + t] * NREL + et[t]], 1);
    }
}

// ---------------- CSR scans / placement ----------------
__device__ int block_exscan256(int v) {
    __shared__ int tmp[256];
    int t = threadIdx.x;
    tmp[t] = v;
    __syncthreads();
    for (int d = 1; d < 256; d <<= 1) {
        int add = (t >= d) ? tmp[t - d] : 0;
        __syncthreads();
        tmp[t] += add;
        __syncthreads();
    }
    return tmp[t] - v;
}

__global__ __launch_bounds__(256) void scanA_kernel(const int* __restrict__ counts,
                                                    int* __restrict__ chunkTot, int nb) {
    int base = blockIdx.x * SCAN_CHUNK + threadIdx.x * 4;
    int s = 0;
#pragma unroll
    for (int i = 0; i < 4; i++) {
        int idx = base + i;
        s += (idx < nb) ? counts[idx] : 0;
    }
    __shared__ int red[256];
    red[threadIdx.x] = s;
    __syncthreads();
    for (int d = 128; d > 0; d >>= 1) {
        if (threadIdx.x < d) red[threadIdx.x] += red[threadIdx.x + d];
        __syncthreads();
    }
    if (threadIdx.x == 0) chunkTot[blockIdx.x] = red[0];
}

__global__ __launch_bounds__(256) void scanB_kernel(const int* __restrict__ chunkTot,
                                                    int* __restrict__ chunkBase, int nChunks) {
    int t = threadIdx.x;
    int v = (t < nChunks) ? chunkTot[t] : 0;
    int ex = block_exscan256(v);
    if (t < nChunks) chunkBase[t] = ex;
}

__global__ __launch_bounds__(256) void scanC_kernel(const int* __restrict__ counts,
                                                    const int* __restrict__ chunkBase,
                                                    int* __restrict__ offs,
                                                    int* __restrict__ cursor, int nb) {
    int base = blockIdx.x * SCAN_CHUNK + threadIdx.x * 4;
    int c[4], s = 0;
#pragma unroll
    for (int i = 0; i < 4; i++) {
        int idx = base + i;
        c[i] = (idx < nb) ? counts[idx] : 0;
        s += c[i];
    }
    int pos = block_exscan256(s) + chunkBase[blockIdx.x];
#pragma unroll
    for (int i = 0; i < 4; i++) {
        int idx = base + i;
        if (idx < nb) {
            offs[idx] = pos;
            cursor[idx] = pos;
        }
        pos += c[i];
    }
}

__global__ void place_kernel(const int* __restrict__ ei, const int* __restrict__ et,
                             int* __restrict__ cursor, int* __restrict__ csr, int E) {
    int e = blockIdx.x * 256 + threadIdx.x;
    if (e >= E) return;
    int b = ei[E + e] * NREL + et[e];
    int p = atomicAdd(&cursor[b], 1);
    csr[p] = ei[e];
}

// ---------------- gather-aggregate: 16 lanes/bucket, coalesced index prefetch ----------------
__global__ __launch_bounds__(256) void agg_kernel(
    const unsigned short* __restrict__ feat, const int* __restrict__ csr,
    const int* __restrict__ offs, const int* __restrict__ counts,
    unsigned short* __restrict__ agg, int nb) {
    int l16 = threadIdx.x & 15;
    int g = (blockIdx.x * 256 + threadIdx.x) >> 4;
    if (g >= nb) return;
    int start = offs[g];
    int cnt = counts[g];
    float acc[8];
#pragma unroll
    for (int j = 0; j < 8; j++) acc[j] = 0.f;
    for (int base = 0; base < cnt; base += 16) {
        int m = cnt - base;
        if (m > 16) m = 16;
        // coalesced: lane l16 fetches index base+l16 (clamped); broadcast below
        int pick = (l16 < m) ? l16 : (m - 1);
        int idx = csr[start + base + pick];
        for (int j = 0; j < m; j++) {
            int s = __shfl(idx, j, 16);  // broadcast within 16-lane group
            short8 u = *(const short8*)(feat + (size_t)s * DIM_IN + l16 * 8);
#pragma unroll
            for (int c = 0; c < 8; c++) acc[c] += bf2f((unsigned short)u[c]);
        }
    }
    float sc = (cnt > 0) ? (1.0f / (float)cnt) : 0.f;
    short8 o;
#pragma unroll
    for (int j = 0; j < 8; j++) o[j] = (short)f2bf(acc[j] * sc);
    *(short8*)(agg + (size_t)g * DIM_IN + l16 * 8) = o;
}

// ---------------- MFMA GEMM, m97 structure, BK=64 (2 panels of 32) ----------------
// BM=128, BN=NOUT. 4 waves: wave (wm,wn) computes 64 rows x NOUT/2 cols.
// LDS per k-iter: sA = 2 panels [128][32], sB = 2 panels [NOUT][32].
template <int NOUT, bool STORE_BF16_RELU>
__global__ __launch_bounds__(256) void mfma_gemm_kernel(
    const unsigned short* __restrict__ xb,   // [N,128] bf16
    const unsigned short* __restrict__ agg,  // [N,512] bf16 (normalized)
    const unsigned short* __restrict__ Wt,   // [NOUT,640] bf16 (transposed)
    const float* __restrict__ bias,          // [NOUT]
    void* __restrict__ outp,                 // bf16 [N,128] or f32 [N,NOUT]
    int N) {
    constexpr int NT = NOUT / 32;          // n-tiles per wave (4 or 3)
    constexpr int ACH = 128 * 8;           // A 16B-chunks per iter (1024)
    constexpr int BCH = NOUT * 8;          // B 16B-chunks per iter
    constexpr int APAN = 128 * 32;         // shorts per A panel
    constexpr int BPAN = NOUT * 32;        // shorts per B panel
    __shared__ unsigned short sA[2 * APAN];
    __shared__ unsigned short sB[2 * BPAN];
    const int t = threadIdx.x;
    const int w = t >> 6;
    const int lane = t & 63;
    const int q = lane >> 4;
    const int l15 = lane & 15;
    const int wm = w >> 1, wn = w & 1;
    const int m0 = blockIdx.x * 128;

    floatx4 acc[4][NT];
#pragma unroll
    for (int mt = 0; mt < 4; mt++)
#pragma unroll
        for (int nt = 0; nt < NT; nt++) acc[mt][nt] = (floatx4)0.f;

    for (int ks = 0; ks < KTOT / 64; ks++) {
        const int k0 = ks * 64;
        // ---- stage A ----
#pragma unroll
        for (int r = 0; r < ACH / 256; r++) {
            int idx = t + r * 256;
            int panel = idx >> 9;           // 512 chunks per panel
            int rem = idx & 511;
            int row = rem >> 2, ch = rem & 3;
            int rowg = m0 + row;
            if (rowg >= N) rowg = N - 1;
            int col = panel * 32 + ch * 8;
            const unsigned short* gp =
                (k0 < DIM_IN)
                    ? (xb + (size_t)rowg * DIM_IN + k0 + col)
                    : (agg + (size_t)rowg * (NREL * DIM_IN) + (k0 - DIM_IN) + col);
            gload16_lds(gp, sA + (size_t)idx * 8);
        }
        // ---- stage B ----
#pragma unroll
        for (int r = 0; r < BCH / 256; r++) {
            int idx = t + r * 256;
            int panel = idx / (NOUT * 4);
            int rem = idx - panel * (NOUT * 4);
            int nrow = rem >> 2, ch = rem & 3;
            const unsigned short* gp = Wt + (size_t)nrow * KTOT + k0 + panel * 32 + ch * 8;
            gload16_lds(gp, sB + (size_t)idx * 8);
        }
        __syncthreads();
        // ---- fragments + MFMA, 2 k-subs ----
#pragma unroll
        for (int s = 0; s < 2; s++) {
            short8 aF[4], bF[NT];
#pragma unroll
            for (int mt = 0; mt < 4; mt++)
                aF[mt] = *(const short8*)(sA + s * APAN +
                                          (size_t)(wm * 64 + mt * 16 + l15) * 32 + q * 8);
#pragma unroll
            for (int nt = 0; nt < NT; nt++)
                bF[nt] = *(const short8*)(sB + s * BPAN +
                                          (size_t)(wn * (NOUT / 2) + nt * 16 + l15) * 32 + q * 8);
#pragma unroll
            for (int mt = 0; mt < 4; mt++)
#pragma unroll
                for (int nt = 0; nt < NT; nt++)
                    acc[mt][nt] = __builtin_amdgcn_mfma_f32_16x16x32_bf16(aF[mt], bF[nt],
                                                                          acc[mt][nt], 0, 0, 0);
        }
        __syncthreads();
    }

    // epilogue: C/D layout col=lane&15, row=quad*4+reg
#pragma unroll
    for (int nt = 0; nt < NT; nt++) {
        int colg = wn * (NOUT / 2) + nt * 16 + l15;
        float bv = bias[colg];
#pragma unroll
        for (int mt = 0; mt < 4; mt++) {
            int rbase = m0 + wm * 64 + mt * 16 + q * 4;
#pragma unroll
            for (int r = 0; r < 4; r++) {
                int grow = rbase + r;
                if (grow < N) {
                    float v = acc[mt][nt][r] + bv;
                    if (STORE_BF16_RELU) {
                        v = fmaxf(v, 0.f);
                        ((unsigned short*)outp)[(size_t)grow * NOUT + colg] = f2bf(v);
                    } else {
                        ((float*)outp)[(size_t)grow * NOUT + colg] = v;
                    }
                }
            }
        }
    }
}

extern "C" void kernel_launch(void* const* d_in, const int* in_sizes, int n_in,
                              void* d_out, int out_size, void* d_ws, size_t ws_size,
                              hipStream_t stream) {
    const float* x = (const float*)d_in[0];
    const int* ei = (const int*)d_in[1];
    const int* et = (const int*)d_in[2];
    const float* Wroot1 = (const float*)d_in[3];
    const float* Wrel1 = (const float*)d_in[4];
    const float* b1 = (const float*)d_in[5];
    const float* Wroot2 = (const float*)d_in[6];
    const float* Wrel2 = (const float*)d_in[7];
    const float* b2 = (const float*)d_in[8];
    float* out = (float*)d_out;

    int N = in_sizes[0] / DIM_IN;
    int E = in_sizes[2];
    int nb = N * NREL;
    int nChunks = (nb + SCAN_CHUNK - 1) / SCAN_CHUNK;

    char* p = (char*)d_ws;
    unsigned short* xb = (unsigned short*)p;   p += (size_t)N * DIM_IN * 2;
    unsigned short* hb = (unsigned short*)p;   p += (size_t)N * DIM_IN * 2;
    unsigned short* agg = (unsigned short*)p;  p += (size_t)nb * DIM_IN * 2;
    unsigned short* Wt1 = (unsigned short*)p;  p += (size_t)128 * KTOT * 2;
    unsigned short* Wt2 = (unsigned short*)p;  p += (size_t)96 * KTOT * 2;
    int* counts = (int*)p;                     p += (size_t)nb * 4;
    int* offs = (int*)p;                       p += (size_t)nb * 4;
    int* cursor = (int*)p;                     p += (size_t)nb * 4;
    int* chunkTot = (int*)p;                   p += 256 * 4;
    int* chunkBase = (int*)p;                  p += 256 * 4;
    int* csr = (int*)p;                        p += (size_t)E * 4;
    if ((size_t)(p - (char*)d_ws) > ws_size) return;

    int n4 = N * DIM_IN / 4;
    int prepWork = n4;  // n4 (1.6M) dominates (W: 143k, E: 600k)
    if (prepWork < E) prepWork = E;
    if (prepWork < (128 + 96) * KTOT) prepWork = (128 + 96) * KTOT;

    hipMemsetAsync(counts, 0, (size_t)nb * sizeof(int), stream);
    prep_kernel<<<(prepWork + 255) / 256, 256, 0, stream>>>(
        x, xb, n4, Wroot1, Wrel1, Wt1, Wroot2, Wrel2, Wt2, ei, et, counts, E);
    scanA_kernel<<<nChunks, 256, 0, stream>>>(counts, chunkTot, nb);
    scanB_kernel<<<1, 256, 0, stream>>>(chunkTot, chunkBase, nChunks);
    scanC_kernel<<<nChunks, 256, 0, stream>>>(counts, chunkBase, offs, cursor, nb);
    place_kernel<<<(E + 255) / 256, 256, 0, stream>>>(ei, et, cursor, csr, E);

    int gAgg = (nb * 16 + 255) / 256;
    int gB = (N + 127) / 128;
    // ---- layer 1 ----
    agg_kernel<<<gAgg, 256, 0, stream>>>(xb, csr, offs, counts, agg, nb);
    mfma_gemm_kernel<128, true><<<gB, 256, 0, stream>>>(xb, agg, Wt1, b1, hb, N);
    // ---- layer 2 ----
    agg_kernel<<<gAgg, 256, 0, stream>>>(hb, csr, offs, counts, agg, nb);
    mfma_gemm_kernel<96, false><<<gB, 256, 0, stream>>>(hb, agg, Wt2, b2, out, N);
}